// Round 8
// baseline (961.191 us; speedup 1.0000x reference)
//
#include <hip/hip_runtime.h>

// Problem constants (from reference setup_inputs)
constexpr int GRID_D = 128;
constexpr int BATCHN = 4;
constexpr int C = 64;
constexpr int VOL = GRID_D * GRID_D * GRID_D;      // 2,097,152
constexpr int V = BATCHN * VOL;                    // 8,388,608 voxel ids
constexpr int W = V / 32;                          // 262,144 bitmask words
constexpr int SCAN_BS = 1024;                      // threads per scan block
constexpr int SCAN_NB = W / SCAN_BS;               // 256 scan blocks
constexpr int RPB = 64;                            // ranks per bucket (16 KB out window)

// clang native vector type (works with __builtin_nontemporal_*)
typedef float floatx4 __attribute__((ext_vector_type(4)));

// ---------------- common kernels ----------------

__global__ void zero_ws(uint4* __restrict__ p, int count) {
    int i = blockIdx.x * blockDim.x + threadIdx.x;
    if (i < count) p[i] = uint4{0u, 0u, 0u, 0u};
}

// Mark each point's voxel id in the bitmask; store lin[] for later passes.
__global__ void mark_bits(const int* __restrict__ coords, unsigned* __restrict__ bm,
                          unsigned* __restrict__ lin, int n) {
    int i = blockIdx.x * blockDim.x + threadIdx.x;
    if (i >= n) return;
    int4 co = reinterpret_cast<const int4*>(coords)[i];
    unsigned l = (unsigned)(co.w * VOL + co.x * (GRID_D * GRID_D) + co.y * GRID_D + co.z);
    lin[i] = l;
    atomicOr(&bm[l >> 5], 1u << (l & 31));
}

// Level-1 scan: per-block exclusive scan of popcounts (wp block-local); totals to bs[]
__global__ void scan1(const unsigned* __restrict__ bm, unsigned* __restrict__ wp,
                      unsigned* __restrict__ bs) {
    int idx = blockIdx.x * SCAN_BS + threadIdx.x;
    unsigned pc = __popc(bm[idx]);
    unsigned v = pc;
    #pragma unroll
    for (int d = 1; d < 64; d <<= 1) {
        unsigned t = __shfl_up(v, d, 64);
        if ((threadIdx.x & 63) >= d) v += t;
    }
    __shared__ unsigned wsum[16];
    int wid = threadIdx.x >> 6;
    int lane = threadIdx.x & 63;
    if (lane == 63) wsum[wid] = v;
    __syncthreads();
    if (threadIdx.x < 16) {
        unsigned s = wsum[threadIdx.x];
        #pragma unroll
        for (int d = 1; d < 16; d <<= 1) {
            unsigned t = __shfl_up(s, d, 16);
            if ((threadIdx.x & 15) >= d) s += t;
        }
        wsum[threadIdx.x] = s;
    }
    __syncthreads();
    unsigned waveoff = (wid == 0) ? 0u : wsum[wid - 1];
    wp[idx] = waveoff + v - pc;
    if (threadIdx.x == SCAN_BS - 1) bs[blockIdx.x] = waveoff + v;
}

// Level-2 scan: exclusive scan of 256 block totals in place; grand total -> bs[256]
__global__ void scan2(unsigned* bs) {
    int t = threadIdx.x;  // 256 threads
    unsigned pc = bs[t];
    unsigned v = pc;
    #pragma unroll
    for (int d = 1; d < 64; d <<= 1) {
        unsigned tt = __shfl_up(v, d, 64);
        if ((t & 63) >= d) v += tt;
    }
    __shared__ unsigned wsum[4];
    int wid = t >> 6, lane = t & 63;
    if (lane == 63) wsum[wid] = v;
    __syncthreads();
    if (t < 4) {
        unsigned s = wsum[t];
        #pragma unroll
        for (int d = 1; d < 4; d <<= 1) {
            unsigned tt = __shfl_up(s, d, 4);
            if ((t & 3) >= d) s += tt;
        }
        wsum[t] = s;
    }
    __syncthreads();
    unsigned waveoff = (wid == 0) ? 0u : wsum[wid - 1];
    bs[t] = waveoff + v - pc;
    if (t == SCAN_NB - 1) bs[SCAN_NB] = waveoff + v;
}

// Emit sorted unique ids (as float) at their ranks
__global__ void emit_uniq(const unsigned* __restrict__ bm, const unsigned* __restrict__ wp,
                          const unsigned* __restrict__ bs, float* __restrict__ out) {
    int idx = blockIdx.x * blockDim.x + threadIdx.x;
    unsigned word = bm[idx];
    unsigned base = wp[idx] + bs[idx >> 10];
    while (word) {
        int b = __ffs(word) - 1;
        out[base++] = (float)((idx << 5) + b);
        word &= word - 1;
    }
}

// ---------------- partition path (big ws) ----------------

// Per point: rank + bucket histogram
__global__ void hist_rank(const unsigned* __restrict__ lin, const unsigned* __restrict__ bm,
                          const unsigned* __restrict__ wp, const unsigned* __restrict__ bs,
                          unsigned* __restrict__ rankArr, unsigned* __restrict__ bucketCnt,
                          int n) {
    int i = blockIdx.x * blockDim.x + threadIdx.x;
    if (i >= n) return;
    unsigned l = lin[i], w = l >> 5, b = l & 31;
    unsigned rank = wp[w] + bs[w >> 10] + __popc(bm[w] & ((1u << b) - 1u));
    rankArr[i] = rank;
    atomicAdd(&bucketCnt[rank / RPB], 1u);
}

// Exclusive scan of K<=16384 bucket counts; one 1024-thread block, 16 elems/thread
__global__ void scan_buckets(const unsigned* __restrict__ cnt, unsigned* __restrict__ base,
                             unsigned* __restrict__ pos, int K) {
    int t = threadIdx.x;
    unsigned loc[16];
    unsigned s = 0;
    #pragma unroll
    for (int j = 0; j < 16; j++) {
        int idx = t * 16 + j;
        unsigned c = (idx < K) ? cnt[idx] : 0u;
        loc[j] = s;
        s += c;
    }
    unsigned v = s;
    #pragma unroll
    for (int d = 1; d < 64; d <<= 1) {
        unsigned tt = __shfl_up(v, d, 64);
        if ((t & 63) >= d) v += tt;
    }
    __shared__ unsigned wsum[16];
    int wid = t >> 6, lane = t & 63;
    if (lane == 63) wsum[wid] = v;
    __syncthreads();
    if (t < 16) {
        unsigned x = wsum[t];
        #pragma unroll
        for (int d = 1; d < 16; d <<= 1) {
            unsigned tt = __shfl_up(x, d, 16);
            if ((t & 15) >= d) x += tt;
        }
        wsum[t] = x;
    }
    __syncthreads();
    unsigned waveoff = (wid == 0) ? 0u : wsum[wid - 1];
    unsigned texcl = waveoff + v - s;
    #pragma unroll
    for (int j = 0; j < 16; j++) {
        int idx = t * 16 + j;
        if (idx < K) {
            unsigned bb = texcl + loc[j];
            base[idx] = bb;
            pos[idx] = bb;
        }
    }
    if (t == 1023) base[K] = texcl + s;  // grand total (= n)
}

// Tail: ids = -1 and zero feature rows for rank in [total, n)
__global__ void id_tail(float* __restrict__ out_ids, float* __restrict__ outf,
                        const unsigned* __restrict__ bs, int n) {
    int gid = blockIdx.x * blockDim.x + threadIdx.x;
    int rank = gid >> 4;
    unsigned total = bs[SCAN_NB];
    if (rank >= n || rank < (int)total) return;
    int c4 = gid & 15;
    floatx4 z = {0.f, 0.f, 0.f, 0.f};
    __builtin_nontemporal_store(z, (floatx4*)(outf + (size_t)rank * C + c4 * 4));
    if (c4 == 0) out_ids[rank] = -1.0f;
}

// Move payload into bucket-streamed scratch. 16 threads per point.
// feat read sequential; scratch writes sequential-per-bucket (L2 write-combined).
__global__ void partition(const unsigned* __restrict__ rankArr, const floatx4* __restrict__ feat4,
                          unsigned* __restrict__ bucketPos, floatx4* __restrict__ sfeat,
                          unsigned* __restrict__ stag, int n) {
    int gid = blockIdx.x * blockDim.x + threadIdx.x;
    int pt = gid >> 4, c4 = gid & 15;
    if (pt >= n) return;
    unsigned rank = rankArr[pt];
    unsigned bkt = rank / RPB;
    int lane = threadIdx.x & 63;
    unsigned slot = 0;
    if ((lane & 15) == 0) slot = atomicAdd(&bucketPos[bkt], 1u);
    slot = __shfl(slot, lane & 48, 64);
    floatx4 v = __builtin_nontemporal_load(&feat4[(size_t)pt * 16 + c4]);
    sfeat[(size_t)slot * 16 + c4] = v;
    if (c4 == 0) stag[slot] = rank;
}

// Workgroup per bucket: sequential scratch reads; writes confined to the bucket's
// 16 KB output window. First contributor per rank stores; others -> overflow list.
__global__ void reduce_buckets(const unsigned* __restrict__ base, const floatx4* __restrict__ sfeat,
                               const unsigned* __restrict__ stag, unsigned* __restrict__ seen,
                               uint2* __restrict__ ovf, unsigned* __restrict__ ovfCnt,
                               float* __restrict__ outf) {
    __shared__ char pad[33000];  // cap occupancy at ~4 wg/CU so L2 windows fit
    int b = blockIdx.x;
    unsigned s0 = base[b], s1 = base[b + 1];
    if (s1 < s0) { volatile char* q = pad; *q = 1; }  // never true; keeps pad alive
    int grp = threadIdx.x >> 4, c4 = threadIdx.x & 15;
    int lane = threadIdx.x & 63;
    for (unsigned m = s0 + grp; m < s1; m += 16) {  // 256 threads = 16 row-groups
        unsigned r = stag[m];
        unsigned first = 0;
        if (c4 == 0) {
            unsigned bit = 1u << (r & 31);
            unsigned old = atomicOr(&seen[r >> 5], bit);
            first = (old & bit) ? 0u : 1u;
            if (!first) {
                unsigned o = atomicAdd(ovfCnt, 1u);
                ovf[o] = uint2{r, m};
            }
        }
        first = __shfl(first, lane & 48, 64);
        floatx4 v = sfeat[(size_t)m * 16 + c4];
        if (first)
            __builtin_nontemporal_store(v, (floatx4*)(outf + (size_t)r * C + c4 * 4));
    }
}

// Apply duplicate contributors (reads scratch rows) via atomics.
__global__ void ovf_apply2(const uint2* __restrict__ ovf, const unsigned* __restrict__ ovfCnt,
                           const floatx4* __restrict__ sfeat, float* __restrict__ outf) {
    unsigned mcount = *ovfCnt;
    unsigned stride = gridDim.x * blockDim.x;
    for (unsigned idx = blockIdx.x * blockDim.x + threadIdx.x; idx < mcount * 16; idx += stride) {
        unsigned e = idx >> 4, c4 = idx & 15;
        uint2 rp = ovf[e];
        floatx4 v = sfeat[(size_t)rp.y * 16 + c4];
        float* dst = outf + (size_t)rp.x * C + c4 * 4;
        atomicAdd(dst + 0, v.x);
        atomicAdd(dst + 1, v.y);
        atomicAdd(dst + 2, v.z);
        atomicAdd(dst + 3, v.w);
    }
}

// ---------------- fallback path (round-7 gather, small ws) ----------------

__global__ void rank_slot(const unsigned* __restrict__ lin, const unsigned* __restrict__ bm,
                          const unsigned* __restrict__ wp, const unsigned* __restrict__ bs,
                          unsigned* __restrict__ metau, uint2* __restrict__ ovf,
                          unsigned* __restrict__ ovfCnt, int n) {
    int i = blockIdx.x * blockDim.x + threadIdx.x;
    if (i >= n) return;
    unsigned l = lin[i];
    unsigned w = l >> 5, b = l & 31;
    unsigned rank = wp[w] + bs[w >> 10] + __popc(bm[w] & ((1u << b) - 1u));
    unsigned old = atomicAdd(&metau[rank * 4], 1u);
    if (old == 0) metau[rank * 4 + 1] = (unsigned)i;
    else if (old == 1) metau[rank * 4 + 2] = (unsigned)i;
    else {
        unsigned o = atomicAdd(ovfCnt, 1u);
        ovf[o] = uint2{rank, (unsigned)i};
    }
}

__global__ void gather_feat(const floatx4* __restrict__ feat4, const uint4* __restrict__ meta,
                            float* __restrict__ out_ids, float* __restrict__ outf, int n) {
    int stride = gridDim.x * blockDim.x;
    int total = n * 16;
    for (int gid = blockIdx.x * blockDim.x + threadIdx.x; gid < total; gid += stride) {
        int rank = gid >> 4;
        int c4 = gid & 15;
        uint4 m = meta[rank];
        floatx4 v = {0.f, 0.f, 0.f, 0.f};
        if (m.x >= 1) {
            v = feat4[(size_t)m.y * 16 + c4];
            if (m.x >= 2) v += feat4[(size_t)m.z * 16 + c4];
        } else if (c4 == 0) {
            out_ids[rank] = -1.0f;
        }
        __builtin_nontemporal_store(v, (floatx4*)(outf + (size_t)rank * C + c4 * 4));
    }
}

__global__ void ovf_apply(const uint2* __restrict__ ovf, const unsigned* __restrict__ ovfCnt,
                          const floatx4* __restrict__ feat4, float* __restrict__ outf) {
    unsigned m = *ovfCnt;
    unsigned stride = gridDim.x * blockDim.x;
    for (unsigned idx = blockIdx.x * blockDim.x + threadIdx.x; idx < m * 16; idx += stride) {
        unsigned e = idx >> 4, c4 = idx & 15;
        uint2 rp = ovf[e];
        floatx4 v = feat4[(size_t)rp.y * 16 + c4];
        float* dst = outf + (size_t)rp.x * C + c4 * 4;
        atomicAdd(dst + 0, v.x);
        atomicAdd(dst + 1, v.y);
        atomicAdd(dst + 2, v.z);
        atomicAdd(dst + 3, v.w);
    }
}

// ---------------- launch ----------------

extern "C" void kernel_launch(void* const* d_in, const int* in_sizes, int n_in,
                              void* d_out, int out_size, void* d_ws, size_t ws_size,
                              hipStream_t stream) {
    const int* coords = (const int*)d_in[0];
    const float* feat = (const float*)d_in[1];
    int n = in_sizes[0] / 4;  // N points
    int K = (n + RPB - 1) / RPB;

    float* out_ids = (float*)d_out;
    float* out_feat = (float*)d_out + n;

    // ---- partition-path layout ----
    size_t off = 0;
    unsigned* base_ws = (unsigned*)d_ws;
    auto alloc = [&](size_t words) { unsigned* p = base_ws + off; off += words; return p; };
    unsigned* seen      = alloc((size_t)n / 32);    // zeroed
    unsigned* bucketCnt = alloc((size_t)K);         // zeroed
    unsigned* ovfCnt    = alloc(64);                // zeroed
    unsigned* bm        = alloc(W);                 // zeroed
    size_t zero_words = off;
    unsigned* wp        = alloc(W);
    unsigned* bs        = alloc(SCAN_NB + 64);
    unsigned* lin       = alloc((size_t)n);
    unsigned* rankArr   = alloc((size_t)n);
    unsigned* bbase     = alloc((size_t)K + 64);
    unsigned* bpos      = alloc((size_t)K + 64);
    uint2*    ovf       = (uint2*)alloc(2 * (size_t)n);
    unsigned* stag      = alloc((size_t)n);
    off = (off + 63) & ~(size_t)63;                 // 256B-align payload scratch
    floatx4*  sfeat     = (floatx4*)(base_ws + off);
    off += (size_t)n * 64;
    size_t need_bytes = off * 4;

    if (ws_size >= need_bytes && K <= 16384 && (n % 64) == 0) {
        int zu4 = (int)(zero_words / 4);
        zero_ws<<<(zu4 + 255) / 256, 256, 0, stream>>>((uint4*)d_ws, zu4);
        mark_bits<<<(n + 255) / 256, 256, 0, stream>>>(coords, bm, lin, n);
        scan1<<<SCAN_NB, SCAN_BS, 0, stream>>>(bm, wp, bs);
        scan2<<<1, SCAN_NB, 0, stream>>>(bs);
        emit_uniq<<<W / 256, 256, 0, stream>>>(bm, wp, bs, out_ids);
        hist_rank<<<(n + 255) / 256, 256, 0, stream>>>(lin, bm, wp, bs, rankArr, bucketCnt, n);
        scan_buckets<<<1, 1024, 0, stream>>>(bucketCnt, bbase, bpos, K);
        id_tail<<<(n * 16) / 256, 256, 0, stream>>>(out_ids, out_feat, bs, n);
        partition<<<(n * 16) / 256, 256, 0, stream>>>(rankArr, (const floatx4*)feat,
                                                      bpos, sfeat, stag, n);
        reduce_buckets<<<K, 256, 0, stream>>>(bbase, sfeat, stag, seen, ovf, ovfCnt, out_feat);
        ovf_apply2<<<128, 256, 0, stream>>>(ovf, ovfCnt, sfeat, out_feat);
    } else {
        // ---- fallback: round-7 gather path ----
        unsigned* metau   = (unsigned*)d_ws;         // 4n words, zeroed
        unsigned* ovfCnt2 = metau + 4 * (size_t)n;   // 64 words, zeroed
        unsigned* bm2     = ovfCnt2 + 64;            // W words, zeroed
        unsigned* wp2     = bm2 + W;
        unsigned* bs2     = wp2 + W;
        unsigned* lin2    = bs2 + SCAN_NB + 64;
        uint2*    ovf2    = (uint2*)(lin2 + n);
        size_t zw = 4 * (size_t)n + 64 + W;
        int zu4 = (int)(zw / 4);
        zero_ws<<<(zu4 + 255) / 256, 256, 0, stream>>>((uint4*)d_ws, zu4);
        mark_bits<<<(n + 255) / 256, 256, 0, stream>>>(coords, bm2, lin2, n);
        scan1<<<SCAN_NB, SCAN_BS, 0, stream>>>(bm2, wp2, bs2);
        scan2<<<1, SCAN_NB, 0, stream>>>(bs2);
        emit_uniq<<<W / 256, 256, 0, stream>>>(bm2, wp2, bs2, out_ids);
        rank_slot<<<(n + 255) / 256, 256, 0, stream>>>(lin2, bm2, wp2, bs2, metau,
                                                       ovf2, ovfCnt2, n);
        gather_feat<<<16384, 256, 0, stream>>>((const floatx4*)feat, (const uint4*)metau,
                                               out_ids, out_feat, n);
        ovf_apply<<<128, 256, 0, stream>>>(ovf2, ovfCnt2, (const floatx4*)feat, out_feat);
    }
}

// Round 9
// 238.878 us; speedup vs baseline: 4.0238x; 4.0238x over previous
//
#include <hip/hip_runtime.h>

// Problem constants (from reference setup_inputs)
constexpr int GRID_D = 128;
constexpr int BATCHN = 4;
constexpr int C = 64;
constexpr int VOL = GRID_D * GRID_D * GRID_D;      // 2,097,152
constexpr int V = BATCHN * VOL;                    // 8,388,608 voxel ids
constexpr int W = V / 32;                          // 262,144 bitmask words
constexpr int SCAN_BS = 1024;                      // threads per scan block
constexpr int SCAN_NB = W / SCAN_BS;               // 256 scan blocks

typedef float floatx4 __attribute__((ext_vector_type(4)));

// ---------------- kernels ----------------

// Zero the 2 MB bitmask+dup region
__global__ void zero_ws(uint4* __restrict__ p, int count) {
    int i = blockIdx.x * blockDim.x + threadIdx.x;
    if (i < count) p[i] = uint4{0u, 0u, 0u, 0u};
}

// Mark each point's voxel id in the bitmask; store lin[]; second hit marks dup.
__global__ void mark_bits(const int* __restrict__ coords, unsigned* __restrict__ bm,
                          unsigned* __restrict__ dup, unsigned* __restrict__ lin, int n) {
    int i = blockIdx.x * blockDim.x + threadIdx.x;
    if (i >= n) return;
    int4 co = reinterpret_cast<const int4*>(coords)[i];
    unsigned l = (unsigned)(co.w * VOL + co.x * (GRID_D * GRID_D) + co.y * GRID_D + co.z);
    lin[i] = l;
    unsigned bit = 1u << (l & 31);
    unsigned old = atomicOr(&bm[l >> 5], bit);
    if (old & bit) atomicOr(&dup[l >> 5], bit);
}

// Level-1 scan: per-block exclusive scan of popcounts (wp block-local); totals to bs[]
__global__ void scan1(const unsigned* __restrict__ bm, unsigned* __restrict__ wp,
                      unsigned* __restrict__ bs) {
    int idx = blockIdx.x * SCAN_BS + threadIdx.x;
    unsigned pc = __popc(bm[idx]);
    unsigned v = pc;
    #pragma unroll
    for (int d = 1; d < 64; d <<= 1) {
        unsigned t = __shfl_up(v, d, 64);
        if ((threadIdx.x & 63) >= d) v += t;
    }
    __shared__ unsigned wsum[16];
    int wid = threadIdx.x >> 6;
    int lane = threadIdx.x & 63;
    if (lane == 63) wsum[wid] = v;
    __syncthreads();
    if (threadIdx.x < 16) {
        unsigned s = wsum[threadIdx.x];
        #pragma unroll
        for (int d = 1; d < 16; d <<= 1) {
            unsigned t = __shfl_up(s, d, 16);
            if ((threadIdx.x & 15) >= d) s += t;
        }
        wsum[threadIdx.x] = s;
    }
    __syncthreads();
    unsigned waveoff = (wid == 0) ? 0u : wsum[wid - 1];
    wp[idx] = waveoff + v - pc;
    if (threadIdx.x == SCAN_BS - 1) bs[blockIdx.x] = waveoff + v;
}

// Level-2 scan: exclusive scan of 256 block totals in place; grand total -> bs[256]
__global__ void scan2(unsigned* bs) {
    int t = threadIdx.x;  // 256 threads
    unsigned pc = bs[t];
    unsigned v = pc;
    #pragma unroll
    for (int d = 1; d < 64; d <<= 1) {
        unsigned tt = __shfl_up(v, d, 64);
        if ((t & 63) >= d) v += tt;
    }
    __shared__ unsigned wsum[4];
    int wid = t >> 6, lane = t & 63;
    if (lane == 63) wsum[wid] = v;
    __syncthreads();
    if (t < 4) {
        unsigned s = wsum[t];
        #pragma unroll
        for (int d = 1; d < 4; d <<= 1) {
            unsigned tt = __shfl_up(s, d, 4);
            if ((t & 3) >= d) s += tt;
        }
        wsum[t] = s;
    }
    __syncthreads();
    unsigned waveoff = (wid == 0) ? 0u : wsum[wid - 1];
    bs[t] = waveoff + v - pc;
    if (t == SCAN_NB - 1) bs[SCAN_NB] = waveoff + v;
}

// Emit sorted unique ids (as float) at their ranks
__global__ void emit_uniq(const unsigned* __restrict__ bm, const unsigned* __restrict__ wp,
                          const unsigned* __restrict__ bs, float* __restrict__ out) {
    int idx = blockIdx.x * blockDim.x + threadIdx.x;
    unsigned word = bm[idx];
    unsigned base = wp[idx] + bs[idx >> 10];
    while (word) {
        int b = __ffs(word) - 1;
        out[base++] = (float)((idx << 5) + b);
        word &= word - 1;
    }
}

// Tail: ids[rank] = -1 and feature rows = 0 for rank in [total, n)
__global__ void tail_fill(float* __restrict__ out_ids, float* __restrict__ outf,
                          const unsigned* __restrict__ bs, int n) {
    int gid = blockIdx.x * blockDim.x + threadIdx.x;  // one float4 per thread
    int rank = gid >> 4;
    unsigned total = bs[SCAN_NB];
    if (rank >= n || rank < (int)total) return;
    reinterpret_cast<float4*>(outf)[gid] = float4{0.f, 0.f, 0.f, 0.f};
    if ((gid & 15) == 0) out_ids[rank] = -1.0f;
}

// Zero output rows of voxels with >1 contributor (they get atomicAdd'ed)
__global__ void zero_dup(const unsigned* __restrict__ bm, const unsigned* __restrict__ dup,
                         const unsigned* __restrict__ wp, const unsigned* __restrict__ bs,
                         float* __restrict__ outf) {
    int idx = blockIdx.x * blockDim.x + threadIdx.x;
    unsigned d = dup[idx];
    if (!d) return;
    unsigned word = bm[idx];
    unsigned base = wp[idx] + bs[idx >> 10];
    while (d) {
        int b = __ffs(d) - 1;
        unsigned rank = base + __popc(word & ((1u << b) - 1u));
        float4* p = reinterpret_cast<float4*>(outf + (size_t)rank * C);
        #pragma unroll
        for (int i = 0; i < 16; i++) p[i] = float4{0.f, 0.f, 0.f, 0.f};
        d &= d - 1;
    }
}

// Scatter features: plain float4 store for singleton voxels, atomicAdd for dups.
// 16 threads per point (one float4 each) -> 4 points per wave, 256B contiguous stores.
__global__ void scatter_feat(const unsigned* __restrict__ lin, const floatx4* __restrict__ feat4,
                             const unsigned* __restrict__ bm, const unsigned* __restrict__ dup,
                             const unsigned* __restrict__ wp, const unsigned* __restrict__ bs,
                             float* __restrict__ outf, int n) {
    int gid = blockIdx.x * blockDim.x + threadIdx.x;
    int pt = gid >> 4;
    int c4 = gid & 15;
    if (pt >= n) return;
    unsigned l = lin[pt];
    unsigned w = l >> 5, b = l & 31;
    unsigned rank = wp[w] + bs[w >> 10] + __popc(bm[w] & ((1u << b) - 1u));
    floatx4 v = feat4[(size_t)pt * 16 + c4];
    float* dst = outf + (size_t)rank * C + c4 * 4;
    if (dup[w] & (1u << b)) {
        atomicAdd(dst + 0, v.x);
        atomicAdd(dst + 1, v.y);
        atomicAdd(dst + 2, v.z);
        atomicAdd(dst + 3, v.w);
    } else {
        *reinterpret_cast<floatx4*>(dst) = v;
    }
}

// ---------------- launch ----------------

extern "C" void kernel_launch(void* const* d_in, const int* in_sizes, int n_in,
                              void* d_out, int out_size, void* d_ws, size_t ws_size,
                              hipStream_t stream) {
    const int* coords = (const int*)d_in[0];
    const float* feat = (const float*)d_in[1];
    int n = in_sizes[0] / 4;  // N points

    float* out_ids = (float*)d_out;            // [n] unique ids (float), -1 padded
    float* out_feat = (float*)d_out + n;       // [n][C] scattered features

    unsigned* bm = (unsigned*)d_ws;            // bitmask, W words (zeroed)
    unsigned* dup = bm + W;                    // duplicate bitmask, W words (zeroed)
    unsigned* wp = dup + W;                    // word prefix (block-local), W words
    unsigned* bs = wp + W;                     // block sums + total, SCAN_NB+1 words
    unsigned* lin = bs + SCAN_NB + 64;         // per-point linear id, n words

    int zero_u4 = (2 * W) / 4;
    zero_ws<<<(zero_u4 + 255) / 256, 256, 0, stream>>>((uint4*)bm, zero_u4);

    mark_bits<<<(n + 255) / 256, 256, 0, stream>>>(coords, bm, dup, lin, n);
    scan1<<<SCAN_NB, SCAN_BS, 0, stream>>>(bm, wp, bs);
    scan2<<<1, SCAN_NB, 0, stream>>>(bs);
    emit_uniq<<<W / 256, 256, 0, stream>>>(bm, wp, bs, out_ids);
    tail_fill<<<(n * 16 + 255) / 256, 256, 0, stream>>>(out_ids, out_feat, bs, n);
    zero_dup<<<W / 256, 256, 0, stream>>>(bm, dup, wp, bs, out_feat);

    int scatter_threads = n * 16;  // one float4 per thread
    scatter_feat<<<(scatter_threads + 255) / 256, 256, 0, stream>>>(
        lin, (const floatx4*)feat, bm, dup, wp, bs, out_feat, n);
}

// Round 10
// 225.634 us; speedup vs baseline: 4.2600x; 1.0587x over previous
//
#include <hip/hip_runtime.h>

// Problem constants (from reference setup_inputs)
constexpr int GRID_D = 128;
constexpr int BATCHN = 4;
constexpr int C = 64;
constexpr int VOL = GRID_D * GRID_D * GRID_D;      // 2,097,152
constexpr int V = BATCHN * VOL;                    // 8,388,608 voxel ids
constexpr int W = V / 32;                          // 262,144 bitmask words
constexpr int SCAN_BS = 1024;                      // threads per scan block
constexpr int SCAN_NB = W / SCAN_BS;               // 256 scan blocks

typedef float floatx4 __attribute__((ext_vector_type(4)));

// ---------------- kernels ----------------

// Zero the 2 MB bitmask+dup region
__global__ void zero_ws(uint4* __restrict__ p, int count) {
    int i = blockIdx.x * blockDim.x + threadIdx.x;
    if (i < count) p[i] = uint4{0u, 0u, 0u, 0u};
}

// Mark each point's voxel id in the bitmask; store lin[]; second hit marks dup.
__global__ void mark_bits(const int* __restrict__ coords, unsigned* __restrict__ bm,
                          unsigned* __restrict__ dup, unsigned* __restrict__ lin, int n) {
    int i = blockIdx.x * blockDim.x + threadIdx.x;
    if (i >= n) return;
    int4 co = reinterpret_cast<const int4*>(coords)[i];
    unsigned l = (unsigned)(co.w * VOL + co.x * (GRID_D * GRID_D) + co.y * GRID_D + co.z);
    lin[i] = l;
    unsigned bit = 1u << (l & 31);
    unsigned old = atomicOr(&bm[l >> 5], bit);
    if (old & bit) atomicOr(&dup[l >> 5], bit);
}

// Level-1 scan: per-block exclusive scan of popcounts (wp block-local); totals to bs[]
__global__ void scan1(const unsigned* __restrict__ bm, unsigned* __restrict__ wp,
                      unsigned* __restrict__ bs) {
    int idx = blockIdx.x * SCAN_BS + threadIdx.x;
    unsigned pc = __popc(bm[idx]);
    unsigned v = pc;
    #pragma unroll
    for (int d = 1; d < 64; d <<= 1) {
        unsigned t = __shfl_up(v, d, 64);
        if ((threadIdx.x & 63) >= d) v += t;
    }
    __shared__ unsigned wsum[16];
    int wid = threadIdx.x >> 6;
    int lane = threadIdx.x & 63;
    if (lane == 63) wsum[wid] = v;
    __syncthreads();
    if (threadIdx.x < 16) {
        unsigned s = wsum[threadIdx.x];
        #pragma unroll
        for (int d = 1; d < 16; d <<= 1) {
            unsigned t = __shfl_up(s, d, 16);
            if ((threadIdx.x & 15) >= d) s += t;
        }
        wsum[threadIdx.x] = s;
    }
    __syncthreads();
    unsigned waveoff = (wid == 0) ? 0u : wsum[wid - 1];
    wp[idx] = waveoff + v - pc;
    if (threadIdx.x == SCAN_BS - 1) bs[blockIdx.x] = waveoff + v;
}

// Level-2 scan: exclusive scan of 256 block totals in place; grand total -> bs[256]
__global__ void scan2(unsigned* bs) {
    int t = threadIdx.x;  // 256 threads
    unsigned pc = bs[t];
    unsigned v = pc;
    #pragma unroll
    for (int d = 1; d < 64; d <<= 1) {
        unsigned tt = __shfl_up(v, d, 64);
        if ((t & 63) >= d) v += tt;
    }
    __shared__ unsigned wsum[4];
    int wid = t >> 6, lane = t & 63;
    if (lane == 63) wsum[wid] = v;
    __syncthreads();
    if (t < 4) {
        unsigned s = wsum[t];
        #pragma unroll
        for (int d = 1; d < 4; d <<= 1) {
            unsigned tt = __shfl_up(s, d, 4);
            if ((t & 3) >= d) s += tt;
        }
        wsum[t] = s;
    }
    __syncthreads();
    unsigned waveoff = (wid == 0) ? 0u : wsum[wid - 1];
    bs[t] = waveoff + v - pc;
    if (t == SCAN_NB - 1) bs[SCAN_NB] = waveoff + v;
}

// Emit sorted unique ids (as float) at their ranks
__global__ void emit_uniq(const unsigned* __restrict__ bm, const unsigned* __restrict__ wp,
                          const unsigned* __restrict__ bs, float* __restrict__ out) {
    int idx = blockIdx.x * blockDim.x + threadIdx.x;
    unsigned word = bm[idx];
    unsigned base = wp[idx] + bs[idx >> 10];
    while (word) {
        int b = __ffs(word) - 1;
        out[base++] = (float)((idx << 5) + b);
        word &= word - 1;
    }
}

// Tail: ids[rank] = -1 and feature rows = 0 for rank in [total, n)
__global__ void tail_fill(float* __restrict__ out_ids, float* __restrict__ outf,
                          const unsigned* __restrict__ bs, int n) {
    int gid = blockIdx.x * blockDim.x + threadIdx.x;  // one float4 per thread
    int rank = gid >> 4;
    unsigned total = bs[SCAN_NB];
    if (rank >= n || rank < (int)total) return;
    floatx4 z = {0.f, 0.f, 0.f, 0.f};
    __builtin_nontemporal_store(z, (floatx4*)(outf + (size_t)gid * 4));
    if ((gid & 15) == 0) out_ids[rank] = -1.0f;
}

// Zero output rows of voxels with >1 contributor (they get atomicAdd'ed)
__global__ void zero_dup(const unsigned* __restrict__ bm, const unsigned* __restrict__ dup,
                         const unsigned* __restrict__ wp, const unsigned* __restrict__ bs,
                         float* __restrict__ outf) {
    int idx = blockIdx.x * blockDim.x + threadIdx.x;
    unsigned d = dup[idx];
    if (!d) return;
    unsigned word = bm[idx];
    unsigned base = wp[idx] + bs[idx >> 10];
    while (d) {
        int b = __ffs(d) - 1;
        unsigned rank = base + __popc(word & ((1u << b) - 1u));
        float4* p = reinterpret_cast<float4*>(outf + (size_t)rank * C);
        #pragma unroll
        for (int i = 0; i < 16; i++) p[i] = float4{0.f, 0.f, 0.f, 0.f};
        d &= d - 1;
    }
}

// Scatter features: nontemporal float4 store for singleton voxels, atomicAdd for dups.
// 16 threads per point (one float4 each) -> 4 points per wave, 256B contiguous stores.
__global__ void scatter_feat(const unsigned* __restrict__ lin, const floatx4* __restrict__ feat4,
                             const unsigned* __restrict__ bm, const unsigned* __restrict__ dup,
                             const unsigned* __restrict__ wp, const unsigned* __restrict__ bs,
                             float* __restrict__ outf, int n) {
    int gid = blockIdx.x * blockDim.x + threadIdx.x;
    int pt = gid >> 4;
    int c4 = gid & 15;
    if (pt >= n) return;
    unsigned l = lin[pt];
    unsigned w = l >> 5, b = l & 31;
    unsigned rank = wp[w] + bs[w >> 10] + __popc(bm[w] & ((1u << b) - 1u));
    floatx4 v = __builtin_nontemporal_load(&feat4[(size_t)pt * 16 + c4]);
    float* dst = outf + (size_t)rank * C + c4 * 4;
    if (dup[w] & (1u << b)) {
        atomicAdd(dst + 0, v.x);
        atomicAdd(dst + 1, v.y);
        atomicAdd(dst + 2, v.z);
        atomicAdd(dst + 3, v.w);
    } else {
        __builtin_nontemporal_store(v, reinterpret_cast<floatx4*>(dst));
    }
}

// ---------------- launch ----------------

extern "C" void kernel_launch(void* const* d_in, const int* in_sizes, int n_in,
                              void* d_out, int out_size, void* d_ws, size_t ws_size,
                              hipStream_t stream) {
    const int* coords = (const int*)d_in[0];
    const float* feat = (const float*)d_in[1];
    int n = in_sizes[0] / 4;  // N points

    float* out_ids = (float*)d_out;            // [n] unique ids (float), -1 padded
    float* out_feat = (float*)d_out + n;       // [n][C] scattered features

    unsigned* bm = (unsigned*)d_ws;            // bitmask, W words (zeroed)
    unsigned* dup = bm + W;                    // duplicate bitmask, W words (zeroed)
    unsigned* wp = dup + W;                    // word prefix (block-local), W words
    unsigned* bs = wp + W;                     // block sums + total, SCAN_NB+1 words
    unsigned* lin = bs + SCAN_NB + 64;         // per-point linear id, n words

    int zero_u4 = (2 * W) / 4;
    zero_ws<<<(zero_u4 + 255) / 256, 256, 0, stream>>>((uint4*)bm, zero_u4);

    mark_bits<<<(n + 255) / 256, 256, 0, stream>>>(coords, bm, dup, lin, n);
    scan1<<<SCAN_NB, SCAN_BS, 0, stream>>>(bm, wp, bs);
    scan2<<<1, SCAN_NB, 0, stream>>>(bs);
    emit_uniq<<<W / 256, 256, 0, stream>>>(bm, wp, bs, out_ids);
    tail_fill<<<(n * 16 + 255) / 256, 256, 0, stream>>>(out_ids, out_feat, bs, n);
    zero_dup<<<W / 256, 256, 0, stream>>>(bm, dup, wp, bs, out_feat);

    int scatter_threads = n * 16;  // one float4 per thread
    scatter_feat<<<(scatter_threads + 255) / 256, 256, 0, stream>>>(
        lin, (const floatx4*)feat, bm, dup, wp, bs, out_feat, n);
}